// Round 1
// 569.668 us; speedup vs baseline: 1.1509x; 1.1509x over previous
//
#include <hip/hip_runtime.h>
#include <hip/hip_bf16.h>
#include <cstdint>
#include <cstddef>

// Problem constants (fixed by the reference setup)
#define NE 8
#define NT 16384
#define ND 2048
#define NH 1024

typedef __bf16 bf16;
typedef __bf16 bf16x8 __attribute__((ext_vector_type(8)));
typedef float f32x4 __attribute__((ext_vector_type(4)));

// Address-space casts for global_load_lds.
#define AS1(p) ((__attribute__((address_space(1))) void*)(uintptr_t)(p))
#define AS3(p) ((__attribute__((address_space(3))) void*)(uint32_t)(uintptr_t)(p))
// 16B-wide async global->LDS. HW writes wave-uniform base + lane*16: per-wave
// LDS destinations are exactly contiguous (t*16B), swizzle applied on the
// GLOBAL source address instead (both-sides-or-neither rule).
#define GLDS16(g, l) __builtin_amdgcn_global_load_lds(AS1(g), AS3(l), 16, 0, 0)

// Counted waits / raw barrier. "memory" clobber pins all LDS reads and stage
// issues on the correct side (compiler may NOT hoist ds_reads above these).
#define WAIT_VM(n) asm volatile("s_waitcnt vmcnt(" #n ")" ::: "memory")
#define BAR() asm volatile("s_barrier" ::: "memory")

// LDS XOR swizzle (unchanged from the 0-conflict version): physical 16B slot p
// of row r holds logical col-block p ^ ((r>>1)&3). Staged via pre-swizzled
// global column, read back with kqs = kq ^ ((l16>>1)&3) (lane-invariant term).

__device__ __forceinline__ int expert_of_row(const int* __restrict__ counts, int row0) {
  int e = 0, cum = 0;
#pragma unroll
  for (int i = 0; i < NE; ++i) {
    if (row0 >= cum) e = i;
    cum += counts[i];
  }
  return e;
}

// ---------------- f32 -> bf16 conversion (memory-bound, 8 elem/thread) -------
__global__ void cvt_kernel(const float* __restrict__ src, bf16* __restrict__ dst, int n8) {
  int i = blockIdx.x * blockDim.x + threadIdx.x;
  if (i >= n8) return;
  const f32x4* s = (const f32x4*)src + (size_t)i * 2;
  f32x4 a = s[0];
  f32x4 b = s[1];
  bf16x8 o;
  o[0] = (bf16)a[0]; o[1] = (bf16)a[1]; o[2] = (bf16)a[2]; o[3] = (bf16)a[3];
  o[4] = (bf16)b[0]; o[5] = (bf16)b[1]; o[6] = (bf16)b[2]; o[7] = (bf16)b[3];
  *((bf16x8*)dst + i) = o;
}

// ---------------- GEMM1: h = silu(x @ w1^T) * (x @ w3^T), bf16 out -----------
// Tile: BM=256, BN=128(dual w1+w3), BK=32. 512 thr = 8 waves (2 row x 4 col);
// wave owns 128x32 of BOTH h1,h3 = 8x2 MFMA frags x 2 acc sets.
// 4-deep pipelined LDS: 4 buffers x (A 16K | B1 8K | B3 8K) = 128 KiB.
__global__ __launch_bounds__(512, 2) void gemm1_kernel(
    const bf16* __restrict__ X, const bf16* __restrict__ W1,
    const bf16* __restrict__ W3, const int* __restrict__ counts,
    bf16* __restrict__ Hb) {
  const int cb = blockIdx.x;   // NH/128 = 8
  const int rb = blockIdx.y;   // NT/256 = 64
  const int t = threadIdx.x;
  const int lane = t & 63;
  const int wave = t >> 6;     // 0..7
  const int wr = wave >> 2;    // 0..1 : 128 rows each
  const int wc = wave & 3;     // 0..3 : 32 cols each
  const int l16 = lane & 15;
  const int kq = lane >> 4;
  const int kqs = kq ^ ((l16 >> 1) & 3);

  const int row0 = rb * 256;
  const int e = expert_of_row(counts, row0);

  const bf16* Xe  = X  + (size_t)row0 * ND;
  const bf16* W1e = W1 + (size_t)e * NH * ND + (size_t)cb * 128 * ND;
  const bf16* W3e = W3 + (size_t)e * NH * ND + (size_t)cb * 128 * ND;

  __shared__ __align__(16) bf16 lds[4 * 16384];   // 128 KiB

  const int srow = t >> 2;                             // 0..127
  const int scol = (((t & 3) ^ ((t >> 3) & 3)) * 8);   // swizzled col-block

  const bf16* gA  = Xe  + (size_t)srow * ND + scol;
  const bf16* gB1 = W1e + (size_t)srow * ND + scol;
  const bf16* gB3 = W3e + (size_t)srow * ND + scol;

  const int a_base  = (wr * 128 + l16) * 32 + kqs * 8;
  const int b1_base = 8192  + (wc * 32 + l16) * 32 + kqs * 8;
  const int b3_base = 12288 + (wc * 32 + l16) * 32 + kqs * 8;

  f32x4 acc1[8][2] = {};
  f32x4 acc3[8][2] = {};

  const int NK = ND / 32;   // 64

  // Prologue: stage K-tiles 0,1,2 (12 loads/thread in flight).
#pragma unroll
  for (int p = 0; p < 3; ++p) {
    bf16* buf = lds + p * 16384;
    const int ko = p * 32;
    GLDS16(gA  + ko,                    buf + t * 8);
    GLDS16(gA  + (size_t)128 * ND + ko, buf + 4096 + t * 8);
    GLDS16(gB1 + ko,                    buf + 8192 + t * 8);
    GLDS16(gB3 + ko,                    buf + 12288 + t * 8);
  }

  for (int kt = 0; kt < NK; ++kt) {
    // Derived wait: tiles kt+1,kt+2 (4 loads each) stay in flight.
    if (kt + 2 < NK)      WAIT_VM(8);
    else if (kt + 1 < NK) WAIT_VM(4);
    else                  WAIT_VM(0);
    BAR();
    bf16* buf = lds + (kt & 3) * 16384;
    if (kt + 3 < NK) {
      // buf[(kt+3)&3] == buf[(kt-1)&3]: fully consumed before this barrier.
      bf16* nb = lds + ((kt + 3) & 3) * 16384;
      const int ko = (kt + 3) * 32;
      GLDS16(gA  + ko,                    nb + t * 8);
      GLDS16(gA  + (size_t)128 * ND + ko, nb + 4096 + t * 8);
      GLDS16(gB1 + ko,                    nb + 8192 + t * 8);
      GLDS16(gB3 + ko,                    nb + 12288 + t * 8);
    }

    bf16x8 b1[2], b3[2], a[4];
#pragma unroll
    for (int j = 0; j < 2; ++j) {
      b1[j] = *(const bf16x8*)(buf + b1_base + j * 512);
      b3[j] = *(const bf16x8*)(buf + b3_base + j * 512);
    }
#pragma unroll
    for (int i = 0; i < 4; ++i)
      a[i] = *(const bf16x8*)(buf + a_base + i * 512);
    __builtin_amdgcn_s_setprio(1);
#pragma unroll
    for (int i = 0; i < 4; ++i)
#pragma unroll
      for (int j = 0; j < 2; ++j) {
        acc1[i][j] = __builtin_amdgcn_mfma_f32_16x16x32_bf16(a[i], b1[j], acc1[i][j], 0, 0, 0);
        acc3[i][j] = __builtin_amdgcn_mfma_f32_16x16x32_bf16(a[i], b3[j], acc3[i][j], 0, 0, 0);
      }
    __builtin_amdgcn_s_setprio(0);
#pragma unroll
    for (int i = 0; i < 4; ++i)
      a[i] = *(const bf16x8*)(buf + a_base + (4 + i) * 512);
    __builtin_amdgcn_s_setprio(1);
#pragma unroll
    for (int i = 0; i < 4; ++i)
#pragma unroll
      for (int j = 0; j < 2; ++j) {
        acc1[4 + i][j] = __builtin_amdgcn_mfma_f32_16x16x32_bf16(a[i], b1[j], acc1[4 + i][j], 0, 0, 0);
        acc3[4 + i][j] = __builtin_amdgcn_mfma_f32_16x16x32_bf16(a[i], b3[j], acc3[4 + i][j], 0, 0, 0);
      }
    __builtin_amdgcn_s_setprio(0);
  }

  // Epilogue: C/D layout col=lane&15, row=(lane>>4)*4+reg. silu(a1)*a3 -> bf16.
  const int rbase = row0 + wr * 128 + kq * 4;
  const int cbase = cb * 128 + wc * 32 + l16;
#pragma unroll
  for (int i = 0; i < 8; ++i)
#pragma unroll
    for (int j = 0; j < 2; ++j) {
      const int col = cbase + j * 16;
#pragma unroll
      for (int r = 0; r < 4; ++r) {
        const int row = rbase + i * 16 + r;
        const float v1 = acc1[i][j][r];
        const float v3 = acc3[i][j][r];
        const float hv = (v1 / (1.0f + __expf(-v1))) * v3;
        Hb[(size_t)row * NH + col] = (bf16)hv;
      }
    }
}

// ---------------- GEMM2: out = h @ w2^T, f32 out ------------------------------
// Tile: BM=256, BN=256, BK=32. 8 waves (2x4); wave owns 128x64 = 8x4 frags.
// Same 4-deep pipeline, 4 x (A 16K | B 16K) = 128 KiB LDS.
__global__ __launch_bounds__(512, 2) void gemm2_kernel(
    const bf16* __restrict__ Hb, const bf16* __restrict__ W2,
    const int* __restrict__ counts, float* __restrict__ Out) {
  const int cb = blockIdx.x;   // ND/256 = 8
  const int rb = blockIdx.y;   // NT/256 = 64
  const int t = threadIdx.x;
  const int lane = t & 63;
  const int wave = t >> 6;
  const int wr = wave >> 2;    // 0..1 : 128 rows
  const int wc = wave & 3;     // 0..3 : 64 cols
  const int l16 = lane & 15;
  const int kq = lane >> 4;
  const int kqs = kq ^ ((l16 >> 1) & 3);

  const int row0 = rb * 256;
  const int e = expert_of_row(counts, row0);

  const bf16* He  = Hb + (size_t)row0 * NH;
  const bf16* W2e = W2 + (size_t)e * ND * NH + (size_t)cb * 256 * NH;

  __shared__ __align__(16) bf16 lds[4 * 16384];   // 128 KiB

  const int srow = t >> 2;
  const int scol = (((t & 3) ^ ((t >> 3) & 3)) * 8);

  const bf16* gA = He  + (size_t)srow * NH + scol;
  const bf16* gB = W2e + (size_t)srow * NH + scol;

  const int a_base = (wr * 128 + l16) * 32 + kqs * 8;
  const int b_base = 8192 + (wc * 64 + l16) * 32 + kqs * 8;

  f32x4 acc[8][4] = {};

  const int NK = NH / 32;   // 32

#pragma unroll
  for (int p = 0; p < 3; ++p) {
    bf16* buf = lds + p * 16384;
    const int ko = p * 32;
    GLDS16(gA + ko,                    buf + t * 8);
    GLDS16(gA + (size_t)128 * NH + ko, buf + 4096 + t * 8);
    GLDS16(gB + ko,                    buf + 8192 + t * 8);
    GLDS16(gB + (size_t)128 * NH + ko, buf + 12288 + t * 8);
  }

  for (int kt = 0; kt < NK; ++kt) {
    if (kt + 2 < NK)      WAIT_VM(8);
    else if (kt + 1 < NK) WAIT_VM(4);
    else                  WAIT_VM(0);
    BAR();
    bf16* buf = lds + (kt & 3) * 16384;
    if (kt + 3 < NK) {
      bf16* nb = lds + ((kt + 3) & 3) * 16384;
      const int ko = (kt + 3) * 32;
      GLDS16(gA + ko,                    nb + t * 8);
      GLDS16(gA + (size_t)128 * NH + ko, nb + 4096 + t * 8);
      GLDS16(gB + ko,                    nb + 8192 + t * 8);
      GLDS16(gB + (size_t)128 * NH + ko, nb + 12288 + t * 8);
    }

    bf16x8 b[4], a[4];
#pragma unroll
    for (int j = 0; j < 4; ++j)
      b[j] = *(const bf16x8*)(buf + b_base + j * 512);
#pragma unroll
    for (int i = 0; i < 4; ++i)
      a[i] = *(const bf16x8*)(buf + a_base + i * 512);
    __builtin_amdgcn_s_setprio(1);
#pragma unroll
    for (int i = 0; i < 4; ++i)
#pragma unroll
      for (int j = 0; j < 4; ++j)
        acc[i][j] = __builtin_amdgcn_mfma_f32_16x16x32_bf16(a[i], b[j], acc[i][j], 0, 0, 0);
    __builtin_amdgcn_s_setprio(0);
#pragma unroll
    for (int i = 0; i < 4; ++i)
      a[i] = *(const bf16x8*)(buf + a_base + (4 + i) * 512);
    __builtin_amdgcn_s_setprio(1);
#pragma unroll
    for (int i = 0; i < 4; ++i)
#pragma unroll
      for (int j = 0; j < 4; ++j)
        acc[4 + i][j] = __builtin_amdgcn_mfma_f32_16x16x32_bf16(a[i], b[j], acc[4 + i][j], 0, 0, 0);
    __builtin_amdgcn_s_setprio(0);
  }

  const int rbase = row0 + wr * 128 + kq * 4;
  const int cbase = cb * 256 + wc * 64 + l16;
#pragma unroll
  for (int i = 0; i < 8; ++i)
#pragma unroll
    for (int j = 0; j < 4; ++j) {
      const int col = cbase + j * 16;
#pragma unroll
      for (int r = 0; r < 4; ++r) {
        const int row = rbase + i * 16 + r;
        Out[(size_t)row * ND + col] = acc[i][j][r];
      }
    }
}

// -----------------------------------------------------------------------------
extern "C" void kernel_launch(void* const* d_in, const int* in_sizes, int n_in,
                              void* d_out, int out_size, void* d_ws, size_t ws_size,
                              hipStream_t stream) {
  const float* x     = (const float*)d_in[0];
  const int* counts  = (const int*)d_in[1];
  const float* w1    = (const float*)d_in[2];
  const float* w2    = (const float*)d_in[3];
  const float* w3    = (const float*)d_in[4];
  float* out = (float*)d_out;

  char* ws = (char*)d_ws;
  const size_t xN = (size_t)NT * ND;       // 33.5M elems
  const size_t wN = (size_t)NE * NH * ND;  // 16.8M elems per weight
  bf16* xb  = (bf16*)ws;                                  //  64 MiB
  bf16* w1b = (bf16*)(ws + xN * 2);                       // +32 MiB
  bf16* w3b = (bf16*)(ws + xN * 2 + wN * 2);              // +32 MiB
  bf16* w2b = (bf16*)(ws + xN * 2 + 2 * wN * 2);          // +32 MiB
  bf16* hb  = (bf16*)(ws + xN * 2 + 3 * wN * 2);          // +32 MiB (h: T x H bf16)

  { int n8 = (int)(xN / 8); cvt_kernel<<<dim3((n8 + 255) / 256), dim3(256), 0, stream>>>(x, xb, n8); }
  { int n8 = (int)(wN / 8); cvt_kernel<<<dim3((n8 + 255) / 256), dim3(256), 0, stream>>>(w1, w1b, n8); }
  { int n8 = (int)(wN / 8); cvt_kernel<<<dim3((n8 + 255) / 256), dim3(256), 0, stream>>>(w3, w3b, n8); }
  { int n8 = (int)(wN / 8); cvt_kernel<<<dim3((n8 + 255) / 256), dim3(256), 0, stream>>>(w2, w2b, n8); }

  gemm1_kernel<<<dim3(NH / 128, NT / 256), dim3(512), 0, stream>>>(xb, w1b, w3b, counts, hb);
  gemm2_kernel<<<dim3(ND / 256, NT / 256), dim3(512), 0, stream>>>(hb, w2b, counts, out);
}